// Round 1
// baseline (15361.658 us; speedup 1.0000x reference)
//
#include <hip/hip_runtime.h>
#include <hip/hip_bf16.h>
#include <math.h>

// Problem constants
static constexpr int Bc = 8;
static constexpr int Sc = 512;
static constexpr int Hc = 768;
static constexpr int NHc = 12;
static constexpr int Lc = 12;
static constexpr int Fc = 3072;
static constexpr int DHc = 64;
static constexpr int NTOK = Bc * Sc;      // 4096

// ---------------------------------------------------------------------------
// Embedding + LayerNorm: one block per token, 256 threads, 3 elems/thread
// ---------------------------------------------------------------------------
__global__ __launch_bounds__(256) void embed_ln_kernel(
    const int* __restrict__ ids, const int* __restrict__ seg,
    const float* __restrict__ tok, const float* __restrict__ typ,
    const float* __restrict__ pos, const float* __restrict__ g,
    const float* __restrict__ b, float* __restrict__ out)
{
    int t = blockIdx.x;             // token index 0..NTOK-1
    int si = t % Sc;
    int id = ids[t], sg = seg[t];
    const float* tp = tok + (size_t)id * Hc;
    const float* yp = typ + (size_t)sg * Hc;
    const float* pp = pos + (size_t)si * Hc;

    float e[3];
    float s = 0.f, s2 = 0.f;
#pragma unroll
    for (int j = 0; j < 3; j++) {
        int h = threadIdx.x + j * 256;
        float v = tp[h] + yp[h] + pp[h];
        e[j] = v; s += v; s2 += v * v;
    }
    __shared__ float red[8];
#pragma unroll
    for (int o = 32; o > 0; o >>= 1) { s += __shfl_xor(s, o); s2 += __shfl_xor(s2, o); }
    int lane = threadIdx.x & 63, wid = threadIdx.x >> 6;
    if (lane == 0) { red[wid] = s; red[4 + wid] = s2; }
    __syncthreads();
    if (threadIdx.x == 0) {
        red[0] = red[0] + red[1] + red[2] + red[3];
        red[4] = red[4] + red[5] + red[6] + red[7];
    }
    __syncthreads();
    float mean = red[0] * (1.0f / Hc);
    float var  = red[4] * (1.0f / Hc) - mean * mean;
    float rstd = rsqrtf(var + 1e-12f);
    float* op = out + (size_t)t * Hc;
#pragma unroll
    for (int j = 0; j < 3; j++) {
        int h = threadIdx.x + j * 256;
        op[h] = g[h] * (e[j] - mean) * rstd + b[h];
    }
}

// ---------------------------------------------------------------------------
// (t + residual) -> LayerNorm : one block per token
// ---------------------------------------------------------------------------
__global__ __launch_bounds__(256) void add_ln_kernel(
    const float* __restrict__ tin, const float* __restrict__ res,
    const float* __restrict__ g, const float* __restrict__ b,
    float* __restrict__ out)
{
    int t = blockIdx.x;
    const float* ip = tin + (size_t)t * Hc;
    const float* rp = res + (size_t)t * Hc;

    float e[3];
    float s = 0.f, s2 = 0.f;
#pragma unroll
    for (int j = 0; j < 3; j++) {
        int h = threadIdx.x + j * 256;
        float v = ip[h] + rp[h];
        e[j] = v; s += v; s2 += v * v;
    }
    __shared__ float red[8];
#pragma unroll
    for (int o = 32; o > 0; o >>= 1) { s += __shfl_xor(s, o); s2 += __shfl_xor(s2, o); }
    int lane = threadIdx.x & 63, wid = threadIdx.x >> 6;
    if (lane == 0) { red[wid] = s; red[4 + wid] = s2; }
    __syncthreads();
    if (threadIdx.x == 0) {
        red[0] = red[0] + red[1] + red[2] + red[3];
        red[4] = red[4] + red[5] + red[6] + red[7];
    }
    __syncthreads();
    float mean = red[0] * (1.0f / Hc);
    float var  = red[4] * (1.0f / Hc) - mean * mean;
    float rstd = rsqrtf(var + 1e-12f);
    float* op = out + (size_t)t * Hc;
#pragma unroll
    for (int j = 0; j < 3; j++) {
        int h = threadIdx.x + j * 256;
        op[h] = g[h] * (e[j] - mean) * rstd + b[h];
    }
}

// ---------------------------------------------------------------------------
// FP32 GEMM: C[M,N] = A[M,K] @ W[K,N] + bias  (+ optional exact-erf GELU)
// 128x128 tile, BK=16, 256 threads, 8x8 per thread. All dims divide evenly.
// ---------------------------------------------------------------------------
static constexpr int BM = 128;
static constexpr int BN = 128;
static constexpr int BK = 16;

template <bool GELU>
__global__ __launch_bounds__(256) void gemm_kernel(
    const float* __restrict__ A, const float* __restrict__ W,
    const float* __restrict__ bias, float* __restrict__ C,
    int M, int N, int K)
{
    __shared__ __align__(16) float As[BK][BM];   // A transposed: As[k][m]
    __shared__ __align__(16) float Bs[BK][BN];   // Bs[k][n]

    int tid = threadIdx.x;
    int tx = tid & 15;        // n-direction
    int ty = tid >> 4;        // m-direction
    int m0 = blockIdx.x * BM;
    int n0 = blockIdx.y * BN;

    float acc[8][8] = {};

    for (int k0 = 0; k0 < K; k0 += BK) {
        // Stage A tile (transpose into LDS)
#pragma unroll
        for (int p = 0; p < 2; p++) {
            int row = p * 64 + (tid >> 2);
            int kk4 = (tid & 3) * 4;
            float4 av = *(const float4*)(A + (size_t)(m0 + row) * K + k0 + kk4);
            As[kk4 + 0][row] = av.x;
            As[kk4 + 1][row] = av.y;
            As[kk4 + 2][row] = av.z;
            As[kk4 + 3][row] = av.w;
        }
        // Stage B tile
#pragma unroll
        for (int p = 0; p < 2; p++) {
            int kk = p * 8 + (tid >> 5);
            int c4 = (tid & 31) * 4;
            *(float4*)&Bs[kk][c4] = *(const float4*)(W + (size_t)(k0 + kk) * N + n0 + c4);
        }
        __syncthreads();

#pragma unroll
        for (int kk = 0; kk < BK; kk++) {
            float a[8], bb[8];
            *(float4*)&a[0]  = *(const float4*)&As[kk][ty * 8];
            *(float4*)&a[4]  = *(const float4*)&As[kk][ty * 8 + 4];
            *(float4*)&bb[0] = *(const float4*)&Bs[kk][tx * 8];
            *(float4*)&bb[4] = *(const float4*)&Bs[kk][tx * 8 + 4];
#pragma unroll
            for (int i = 0; i < 8; i++)
#pragma unroll
                for (int j = 0; j < 8; j++)
                    acc[i][j] = fmaf(a[i], bb[j], acc[i][j]);
        }
        __syncthreads();
    }

    // Epilogue: bias (+gelu), store
#pragma unroll
    for (int i = 0; i < 8; i++) {
        int m = m0 + ty * 8 + i;
        float* cp = C + (size_t)m * N + n0 + tx * 8;
#pragma unroll
        for (int j = 0; j < 8; j++) {
            float v = acc[i][j] + bias[n0 + tx * 8 + j];
            if (GELU) v = 0.5f * v * (1.0f + erff(v * 0.70710678118654752f));
            cp[j] = v;
        }
    }
}

// ---------------------------------------------------------------------------
// Fused flash-style attention (fp32).
// Q,K,V: [B,S,H] with head h at columns h*64..h*64+63. Output ctx: [B,S,H].
// Block: 256 threads = 32 q-rows x 8 lane-groups (8 d's each). K/V tiles of
// 64 rows staged in LDS. Online softmax per q-row.
// ---------------------------------------------------------------------------
__global__ __launch_bounds__(256) void attn_kernel(
    const float* __restrict__ Q, const float* __restrict__ Kg,
    const float* __restrict__ V, const float* __restrict__ mask,
    float* __restrict__ O)
{
    int q0 = blockIdx.x * 32;
    int h  = blockIdx.y;
    int bb = blockIdx.z;
    int tid = threadIdx.x;
    int r = tid >> 3;          // q-row within tile: 0..31
    int g = tid & 7;           // d-group: 0..7 (8 d's each)

    __shared__ __align__(16) float Kl[64][64];
    __shared__ __align__(16) float Vl[64][64];
    __shared__ float Ml[64];

    size_t baseQ = ((size_t)(bb * Sc + q0 + r)) * Hc + h * DHc + g * 8;
    float q[8];
    *(float4*)&q[0] = *(const float4*)(Q + baseQ);
    *(float4*)&q[4] = *(const float4*)(Q + baseQ + 4);

    float m = -1e30f, l = 0.f;
    float acc[8] = {};
    const float scale = 0.125f;   // 1/sqrt(64)

    for (int kt = 0; kt < Sc; kt += 64) {
        // stage K,V tiles (64x64) + mask slice
#pragma unroll
        for (int p = 0; p < 4; p++) {
            int id = p * 256 + tid;
            int row = id >> 4;
            int c4 = (id & 15) * 4;
            size_t ga = ((size_t)(bb * Sc + kt + row)) * Hc + h * DHc + c4;
            *(float4*)&Kl[row][c4] = *(const float4*)(Kg + ga);
            *(float4*)&Vl[row][c4] = *(const float4*)(V + ga);
        }
        if (tid < 64) Ml[tid] = (1.0f - mask[bb * Sc + kt + tid]) * -10000.0f;
        __syncthreads();

        for (int kk = 0; kk < 64; kk++) {
            float kv[8];
            *(float4*)&kv[0] = *(const float4*)&Kl[kk][g * 8];
            *(float4*)&kv[4] = *(const float4*)&Kl[kk][g * 8 + 4];
            float s = 0.f;
#pragma unroll
            for (int j = 0; j < 8; j++) s = fmaf(q[j], kv[j], s);
            s += __shfl_xor(s, 1);
            s += __shfl_xor(s, 2);
            s += __shfl_xor(s, 4);
            s = s * scale + Ml[kk];

            float mn = fmaxf(m, s);
            float f = __expf(m - mn);
            float p = __expf(s - mn);
            l = l * f + p;
            m = mn;

            float vv[8];
            *(float4*)&vv[0] = *(const float4*)&Vl[kk][g * 8];
            *(float4*)&vv[4] = *(const float4*)&Vl[kk][g * 8 + 4];
#pragma unroll
            for (int j = 0; j < 8; j++) acc[j] = fmaf(p, vv[j], acc[j] * f);
        }
        __syncthreads();
    }

    float rl = 1.0f / l;
    float o[8];
#pragma unroll
    for (int j = 0; j < 8; j++) o[j] = acc[j] * rl;
    size_t baseO = ((size_t)(bb * Sc + q0 + r)) * Hc + h * DHc + g * 8;
    *(float4*)(O + baseO) = *(float4*)&o[0];
    *(float4*)(O + baseO + 4) = *(float4*)&o[4];
}

// ---------------------------------------------------------------------------
extern "C" void kernel_launch(void* const* d_in, const int* in_sizes, int n_in,
                              void* d_out, int out_size, void* d_ws, size_t ws_size,
                              hipStream_t stream)
{
    const int*   input_ids      = (const int*)  d_in[0];
    const int*   segment_ids    = (const int*)  d_in[1];
    const float* attention_mask = (const float*)d_in[2];
    const float* tok_emb = (const float*)d_in[3];
    const float* pos_emb = (const float*)d_in[4];
    const float* type_emb= (const float*)d_in[5];
    const float* emb_g   = (const float*)d_in[6];
    const float* emb_b   = (const float*)d_in[7];
    const float* Wq  = (const float*)d_in[8];  const float* bq  = (const float*)d_in[9];
    const float* Wk  = (const float*)d_in[10]; const float* bk  = (const float*)d_in[11];
    const float* Wv  = (const float*)d_in[12]; const float* bv  = (const float*)d_in[13];
    const float* Wao = (const float*)d_in[14]; const float* bao = (const float*)d_in[15];
    const float* ln1_g = (const float*)d_in[16]; const float* ln1_b = (const float*)d_in[17];
    const float* Wi  = (const float*)d_in[18]; const float* bi  = (const float*)d_in[19];
    const float* Wio = (const float*)d_in[20]; const float* bio = (const float*)d_in[21];
    const float* ln2_g = (const float*)d_in[22]; const float* ln2_b = (const float*)d_in[23];

    float* out = (float*)d_out;
    float* ws  = (float*)d_ws;

    const size_t NT = (size_t)NTOK * Hc;   // 3,145,728 floats
    float* X  = ws;
    float* Qb = ws + 1 * NT;
    float* Kb = ws + 2 * NT;   // also reused as XA
    float* Vb = ws + 3 * NT;   // also reused as T2
    float* Cb = ws + 4 * NT;
    float* Hb = ws + 5 * NT;   // NTOK * F floats

    embed_ln_kernel<<<NTOK, 256, 0, stream>>>(input_ids, segment_ids, tok_emb,
                                              type_emb, pos_emb, emb_g, emb_b, X);

    dim3 gN(NTOK / BM, Hc / BN);   // 32 x 6
    dim3 gF(NTOK / BM, Fc / BN);   // 32 x 24
    dim3 gA(Sc / 32, NHc, Bc);     // 16 x 12 x 8

    for (int l = 0; l < Lc; l++) {
        const float* wq  = Wq  + (size_t)l * Hc * Hc;
        const float* wk  = Wk  + (size_t)l * Hc * Hc;
        const float* wv  = Wv  + (size_t)l * Hc * Hc;
        const float* wao = Wao + (size_t)l * Hc * Hc;
        const float* wi  = Wi  + (size_t)l * Hc * Fc;
        const float* wio = Wio + (size_t)l * Fc * Hc;

        gemm_kernel<false><<<gN, 256, 0, stream>>>(X,  wq, bq  + (size_t)l * Hc, Qb, NTOK, Hc, Hc);
        gemm_kernel<false><<<gN, 256, 0, stream>>>(X,  wk, bk  + (size_t)l * Hc, Kb, NTOK, Hc, Hc);
        gemm_kernel<false><<<gN, 256, 0, stream>>>(X,  wv, bv  + (size_t)l * Hc, Vb, NTOK, Hc, Hc);

        attn_kernel<<<gA, 256, 0, stream>>>(Qb, Kb, Vb, attention_mask, Cb);

        // attention output dense -> T (alias Qb)
        gemm_kernel<false><<<gN, 256, 0, stream>>>(Cb, wao, bao + (size_t)l * Hc, Qb, NTOK, Hc, Hc);
        // LN(T + X) -> XA (alias Kb)
        add_ln_kernel<<<NTOK, 256, 0, stream>>>(Qb, X, ln1_g + (size_t)l * Hc, ln1_b + (size_t)l * Hc, Kb);

        // FFN in: XA @ Wi + bi, gelu -> Hb
        gemm_kernel<true><<<gF, 256, 0, stream>>>(Kb, wi, bi + (size_t)l * Fc, Hb, NTOK, Fc, Hc);
        // FFN out: Hb @ Wio + bio -> T2 (alias Vb)
        gemm_kernel<false><<<gN, 256, 0, stream>>>(Hb, wio, bio + (size_t)l * Hc, Vb, NTOK, Hc, Fc);
        // LN(T2 + XA) -> next X (or final output)
        float* xout = (l == Lc - 1) ? out : X;
        add_ln_kernel<<<NTOK, 256, 0, stream>>>(Vb, Kb, ln2_g + (size_t)l * Hc, ln2_b + (size_t)l * Hc, xout);
    }
}

// Round 2
// 4839.219 us; speedup vs baseline: 3.1744x; 3.1744x over previous
//
#include <hip/hip_runtime.h>
#include <math.h>

// Problem constants
static constexpr int Bc = 8;
static constexpr int Sc = 512;
static constexpr int Hc = 768;
static constexpr int NHc = 12;
static constexpr int Lc = 12;
static constexpr int Fc = 3072;
static constexpr int DHc = 64;
static constexpr int NTOK = Bc * Sc;      // 4096
static constexpr int QKVN = 3 * Hc;       // 2304

typedef short bf16x8 __attribute__((ext_vector_type(8)));
typedef float f32x4 __attribute__((ext_vector_type(4)));
typedef unsigned short us8 __attribute__((ext_vector_type(8)));

__device__ __forceinline__ unsigned short f2bf(float f) {
    unsigned u = __float_as_uint(f);
    u += 0x7FFF + ((u >> 16) & 1);   // round-to-nearest-even
    return (unsigned short)(u >> 16);
}

#define AS1 __attribute__((address_space(1)))
#define AS3 __attribute__((address_space(3)))
__device__ __forceinline__ void gld_lds16(const void* g, void* l) {
    __builtin_amdgcn_global_load_lds((const AS1 void*)g, (AS3 void*)l, 16, 0, 0);
}

// ---------------------------------------------------------------------------
// Embedding + LayerNorm -> fp32 X and bf16 X
// ---------------------------------------------------------------------------
__global__ __launch_bounds__(256) void embed_ln_kernel(
    const int* __restrict__ ids, const int* __restrict__ seg,
    const float* __restrict__ tok, const float* __restrict__ typ,
    const float* __restrict__ pos, const float* __restrict__ g,
    const float* __restrict__ b, float* __restrict__ outf,
    unsigned short* __restrict__ outb)
{
    int t = blockIdx.x;
    int si = t % Sc;
    int id = ids[t], sg = seg[t];
    const float* tp = tok + (size_t)id * Hc;
    const float* yp = typ + (size_t)sg * Hc;
    const float* pp = pos + (size_t)si * Hc;

    float e[3];
    float s = 0.f, s2 = 0.f;
#pragma unroll
    for (int j = 0; j < 3; j++) {
        int h = threadIdx.x + j * 256;
        float v = tp[h] + yp[h] + pp[h];
        e[j] = v; s += v; s2 += v * v;
    }
    __shared__ float red[8];
#pragma unroll
    for (int o = 32; o > 0; o >>= 1) { s += __shfl_xor(s, o); s2 += __shfl_xor(s2, o); }
    int lane = threadIdx.x & 63, wid = threadIdx.x >> 6;
    if (lane == 0) { red[wid] = s; red[4 + wid] = s2; }
    __syncthreads();
    if (threadIdx.x == 0) {
        red[0] = red[0] + red[1] + red[2] + red[3];
        red[4] = red[4] + red[5] + red[6] + red[7];
    }
    __syncthreads();
    float mean = red[0] * (1.0f / Hc);
    float var  = red[4] * (1.0f / Hc) - mean * mean;
    float rstd = rsqrtf(var + 1e-12f);
    float* op = outf + (size_t)t * Hc;
    unsigned short* ob = outb + (size_t)t * Hc;
#pragma unroll
    for (int j = 0; j < 3; j++) {
        int h = threadIdx.x + j * 256;
        float v = g[h] * (e[j] - mean) * rstd + b[h];
        op[h] = v;
        ob[h] = f2bf(v);
    }
}

// ---------------------------------------------------------------------------
// (t + residual) -> LayerNorm -> fp32 + bf16
// ---------------------------------------------------------------------------
__global__ __launch_bounds__(256) void add_ln_kernel(
    const float* __restrict__ tin, const float* __restrict__ res,
    const float* __restrict__ g, const float* __restrict__ b,
    float* __restrict__ outf, unsigned short* __restrict__ outb)
{
    int t = blockIdx.x;
    const float* ip = tin + (size_t)t * Hc;
    const float* rp = res + (size_t)t * Hc;

    float e[3];
    float s = 0.f, s2 = 0.f;
#pragma unroll
    for (int j = 0; j < 3; j++) {
        int h = threadIdx.x + j * 256;
        float v = ip[h] + rp[h];
        e[j] = v; s += v; s2 += v * v;
    }
    __shared__ float red[8];
#pragma unroll
    for (int o = 32; o > 0; o >>= 1) { s += __shfl_xor(s, o); s2 += __shfl_xor(s2, o); }
    int lane = threadIdx.x & 63, wid = threadIdx.x >> 6;
    if (lane == 0) { red[wid] = s; red[4 + wid] = s2; }
    __syncthreads();
    if (threadIdx.x == 0) {
        red[0] = red[0] + red[1] + red[2] + red[3];
        red[4] = red[4] + red[5] + red[6] + red[7];
    }
    __syncthreads();
    float mean = red[0] * (1.0f / Hc);
    float var  = red[4] * (1.0f / Hc) - mean * mean;
    float rstd = rsqrtf(var + 1e-12f);
    float* op = outf + (size_t)t * Hc;
    unsigned short* ob = outb + (size_t)t * Hc;
#pragma unroll
    for (int j = 0; j < 3; j++) {
        int h = threadIdx.x + j * 256;
        float v = g[h] * (e[j] - mean) * rstd + b[h];
        op[h] = v;
        ob[h] = f2bf(v);
    }
}

// ---------------------------------------------------------------------------
// Weight transpose+convert: src fp32 [K][N] (ld=N) -> dst bf16 [N][K] (ld=K)
// ---------------------------------------------------------------------------
__global__ __launch_bounds__(256) void transpose_conv(
    const float* __restrict__ src, unsigned short* __restrict__ dst,
    int K, int N)
{
    __shared__ float t[32][33];
    int n0 = blockIdx.x * 32, k0 = blockIdx.y * 32;
    int tx = threadIdx.x, ty = threadIdx.y;
#pragma unroll
    for (int j = 0; j < 4; j++)
        t[ty + j * 8][tx] = src[(size_t)(k0 + ty + j * 8) * N + n0 + tx];
    __syncthreads();
#pragma unroll
    for (int j = 0; j < 4; j++)
        dst[(size_t)(n0 + ty + j * 8) * K + k0 + tx] = f2bf(t[tx][ty + j * 8]);
}

__global__ void concat3_kernel(const float* __restrict__ a, const float* __restrict__ b,
                               const float* __restrict__ c, float* __restrict__ o)
{
    int i = blockIdx.x * 256 + threadIdx.x;   // < 2304
    float v = (i < 768) ? a[i] : (i < 1536 ? b[i - 768] : c[i - 1536]);
    o[i] = v;
}

// ---------------------------------------------------------------------------
// BF16 MFMA GEMM: C[M,N] = A[M,K] @ Bt[N,K]^T + bias
// 128x128 tile, BK=64, 4 waves each computing 64x64, 16x16x32 MFMA.
// global_load_lds staging with XOR slot swizzle (slot ^= row&7).
// GELU_BF16: apply exact-erf gelu and store bf16 to Cb; else fp32 to Cf.
// ---------------------------------------------------------------------------
template <bool GELU_BF16>
__global__ __launch_bounds__(256) void gemm_mfma(
    const unsigned short* __restrict__ A,   // [M][K] bf16
    const unsigned short* __restrict__ Bt,  // [N][K] bf16
    const float* __restrict__ bias,         // [N]
    float* __restrict__ Cf,
    unsigned short* __restrict__ Cb,
    int M, int N, int K)
{
    __shared__ __align__(16) unsigned short As[128 * 64];
    __shared__ __align__(16) unsigned short Bs[128 * 64];

    int tid = threadIdx.x;
    int l = tid & 63, w = tid >> 6;
    int m0 = blockIdx.x * 128, n0 = blockIdx.y * 128;
    int lr = l & 15;          // row-in-frag (A) / col-in-frag (B,D)
    int kg = l >> 4;          // k-group 0..3
    int wr = (w >> 1) * 64, wc = (w & 1) * 64;
    int lx = lr & 7;          // swizzle xor for this lane's frag reads

    f32x4 acc[4][4] = {};

    for (int k0 = 0; k0 < K; k0 += 64) {
        // ---- stage A,B tiles: 128 rows x 64 k (bf16), swizzled source ----
#pragma unroll
        for (int p = 0; p < 4; p++) {
            int i = p * 256 + w * 64 + l;
            int row = i >> 3;
            int slot = (i & 7) ^ (row & 7);
            const unsigned short* ga = A + (size_t)(m0 + row) * K + k0 + slot * 8;
            const unsigned short* gb = Bt + (size_t)(n0 + row) * K + k0 + slot * 8;
            unsigned short* la = As + (size_t)(p * 256 + w * 64) * 8;
            unsigned short* lb = Bs + (size_t)(p * 256 + w * 64) * 8;
            gld_lds16(ga, la);
            gld_lds16(gb, lb);
        }
        asm volatile("s_waitcnt vmcnt(0)" ::: "memory");
        __syncthreads();

        // ---- MFMA: 2 k-halves x 4x4 fragments ----
#pragma unroll
        for (int kh = 0; kh < 2; kh++) {
            bf16x8 av[4], bv[4];
#pragma unroll
            for (int f = 0; f < 4; f++) {
                int sl = (kh * 4 + kg) ^ lx;
                av[f] = *(const bf16x8*)(As + (wr + f * 16 + lr) * 64 + sl * 8);
                bv[f] = *(const bf16x8*)(Bs + (wc + f * 16 + lr) * 64 + sl * 8);
            }
#pragma unroll
            for (int i = 0; i < 4; i++)
#pragma unroll
                for (int j = 0; j < 4; j++)
                    acc[i][j] = __builtin_amdgcn_mfma_f32_16x16x32_bf16(
                        av[i], bv[j], acc[i][j], 0, 0, 0);
        }
        __syncthreads();
    }

    // ---- epilogue: D lane map col=l&15, row=(l>>4)*4+r ----
#pragma unroll
    for (int i = 0; i < 4; i++) {
        int rbase = m0 + wr + i * 16 + kg * 4;
#pragma unroll
        for (int j = 0; j < 4; j++) {
            int col = n0 + wc + j * 16 + lr;
            float bcol = bias[col];
#pragma unroll
            for (int r = 0; r < 4; r++) {
                float v = acc[i][j][r] + bcol;
                if (GELU_BF16) {
                    v = 0.5f * v * (1.0f + erff(v * 0.70710678118654752f));
                    Cb[(size_t)(rbase + r) * N + col] = f2bf(v);
                } else {
                    Cf[(size_t)(rbase + r) * N + col] = v;
                }
            }
        }
    }
}

// ---------------------------------------------------------------------------
// Fused flash-style attention (fp32 math), packed QKV [NTOK][2304].
// Output ctx as bf16 [NTOK][768].
// ---------------------------------------------------------------------------
__global__ __launch_bounds__(256) void attn_kernel(
    const float* __restrict__ QKV, const float* __restrict__ mask,
    unsigned short* __restrict__ O)
{
    const int LD = QKVN;
    int q0 = blockIdx.x * 32;
    int h  = blockIdx.y;
    int bb = blockIdx.z;
    int tid = threadIdx.x;
    int r = tid >> 3;          // q-row within tile: 0..31
    int g = tid & 7;           // d-group: 0..7

    __shared__ __align__(16) float Kl[64][64];
    __shared__ __align__(16) float Vl[64][64];
    __shared__ float Ml[64];

    size_t baseQ = ((size_t)(bb * Sc + q0 + r)) * LD + h * DHc + g * 8;
    float q[8];
    *(float4*)&q[0] = *(const float4*)(QKV + baseQ);
    *(float4*)&q[4] = *(const float4*)(QKV + baseQ + 4);

    float m = -1e30f, l = 0.f;
    float acc[8] = {};
    const float scale = 0.125f;

    for (int kt = 0; kt < Sc; kt += 64) {
#pragma unroll
        for (int p = 0; p < 4; p++) {
            int id = p * 256 + tid;
            int row = id >> 4;
            int c4 = (id & 15) * 4;
            size_t ga = ((size_t)(bb * Sc + kt + row)) * LD + h * DHc + c4;
            *(float4*)&Kl[row][c4] = *(const float4*)(QKV + ga + 768);
            *(float4*)&Vl[row][c4] = *(const float4*)(QKV + ga + 1536);
        }
        if (tid < 64) Ml[tid] = (1.0f - mask[bb * Sc + kt + tid]) * -10000.0f;
        __syncthreads();

        for (int kk = 0; kk < 64; kk++) {
            float kv[8];
            *(float4*)&kv[0] = *(const float4*)&Kl[kk][g * 8];
            *(float4*)&kv[4] = *(const float4*)&Kl[kk][g * 8 + 4];
            float s = 0.f;
#pragma unroll
            for (int j = 0; j < 8; j++) s = fmaf(q[j], kv[j], s);
            s += __shfl_xor(s, 1);
            s += __shfl_xor(s, 2);
            s += __shfl_xor(s, 4);
            s = s * scale + Ml[kk];

            float mn = fmaxf(m, s);
            float f = __expf(m - mn);
            float p = __expf(s - mn);
            l = l * f + p;
            m = mn;

            float vv[8];
            *(float4*)&vv[0] = *(const float4*)&Vl[kk][g * 8];
            *(float4*)&vv[4] = *(const float4*)&Vl[kk][g * 8 + 4];
#pragma unroll
            for (int j = 0; j < 8; j++) acc[j] = fmaf(p, vv[j], acc[j] * f);
        }
        __syncthreads();
    }

    float rl = 1.0f / l;
    us8 ob;
#pragma unroll
    for (int j = 0; j < 8; j++) ob[j] = f2bf(acc[j] * rl);
    *(us8*)(O + ((size_t)(bb * Sc + q0 + r)) * Hc + h * DHc + g * 8) = ob;
}

// ---------------------------------------------------------------------------
extern "C" void kernel_launch(void* const* d_in, const int* in_sizes, int n_in,
                              void* d_out, int out_size, void* d_ws, size_t ws_size,
                              hipStream_t stream)
{
    const int*   input_ids      = (const int*)  d_in[0];
    const int*   segment_ids    = (const int*)  d_in[1];
    const float* attention_mask = (const float*)d_in[2];
    const float* tok_emb = (const float*)d_in[3];
    const float* pos_emb = (const float*)d_in[4];
    const float* type_emb= (const float*)d_in[5];
    const float* emb_g   = (const float*)d_in[6];
    const float* emb_b   = (const float*)d_in[7];
    const float* Wq  = (const float*)d_in[8];  const float* bq  = (const float*)d_in[9];
    const float* Wk  = (const float*)d_in[10]; const float* bk  = (const float*)d_in[11];
    const float* Wv  = (const float*)d_in[12]; const float* bv  = (const float*)d_in[13];
    const float* Wao = (const float*)d_in[14]; const float* bao = (const float*)d_in[15];
    const float* ln1_g = (const float*)d_in[16]; const float* ln1_b = (const float*)d_in[17];
    const float* Wi  = (const float*)d_in[18]; const float* bi  = (const float*)d_in[19];
    const float* Wio = (const float*)d_in[20]; const float* bio = (const float*)d_in[21];
    const float* ln2_g = (const float*)d_in[22]; const float* ln2_b = (const float*)d_in[23];

    float* out = (float*)d_out;

    const size_t NT = (size_t)NTOK * Hc;          // 3,145,728
    float* Xf   = (float*)d_ws;
    float* XAf  = Xf + NT;
    float* QKVf = XAf + NT;                        // NTOK*2304 floats
    float* Tf   = QKVf;                            // alias: T written after attn consumed QKV
    unsigned short* Xb  = (unsigned short*)(QKVf + (size_t)NTOK * QKVN);
    unsigned short* XAb = Xb + NT;
    unsigned short* Cb  = XAb + NT;
    unsigned short* Hb  = Cb + NT;                 // NTOK*Fc bf16
    unsigned short* WT  = Hb + (size_t)NTOK * Fc;  // per-layer transposed weights
    unsigned short* WqkvT = WT;                    // [2304][768]
    unsigned short* WaoT  = WqkvT + (size_t)QKVN * Hc;
    unsigned short* WiT   = WaoT + (size_t)Hc * Hc;     // [3072][768]
    unsigned short* WioT  = WiT + (size_t)Fc * Hc;      // [768][3072]
    float* bqkv = (float*)(WioT + (size_t)Hc * Fc);     // [2304]

    embed_ln_kernel<<<NTOK, 256, 0, stream>>>(input_ids, segment_ids, tok_emb,
                                              type_emb, pos_emb, emb_g, emb_b, Xf, Xb);

    dim3 tb(32, 8);
    dim3 gQKV(NTOK / 128, QKVN / 128);   // 32 x 18
    dim3 gH(NTOK / 128, Hc / 128);       // 32 x 6
    dim3 gF(NTOK / 128, Fc / 128);       // 32 x 24
    dim3 gA(Sc / 32, NHc, Bc);           // 16 x 12 x 8

    for (int l = 0; l < Lc; l++) {
        const float* wq  = Wq  + (size_t)l * Hc * Hc;
        const float* wk  = Wk  + (size_t)l * Hc * Hc;
        const float* wv  = Wv  + (size_t)l * Hc * Hc;
        const float* wao = Wao + (size_t)l * Hc * Hc;
        const float* wi  = Wi  + (size_t)l * Hc * Fc;
        const float* wio = Wio + (size_t)l * Fc * Hc;

        // weight prep (bf16, transposed to [N][K])
        transpose_conv<<<dim3(Hc / 32, Hc / 32), tb, 0, stream>>>(wq, WqkvT, Hc, Hc);
        transpose_conv<<<dim3(Hc / 32, Hc / 32), tb, 0, stream>>>(wk, WqkvT + (size_t)Hc * Hc, Hc, Hc);
        transpose_conv<<<dim3(Hc / 32, Hc / 32), tb, 0, stream>>>(wv, WqkvT + (size_t)2 * Hc * Hc, Hc, Hc);
        transpose_conv<<<dim3(Hc / 32, Hc / 32), tb, 0, stream>>>(wao, WaoT, Hc, Hc);
        transpose_conv<<<dim3(Fc / 32, Hc / 32), tb, 0, stream>>>(wi, WiT, Hc, Fc);
        transpose_conv<<<dim3(Hc / 32, Fc / 32), tb, 0, stream>>>(wio, WioT, Fc, Hc);
        concat3_kernel<<<QKVN / 256, 256, 0, stream>>>(bq + (size_t)l * Hc, bk + (size_t)l * Hc,
                                                       bv + (size_t)l * Hc, bqkv);

        // fused QKV GEMM: [4096,768] @ [768,2304]
        gemm_mfma<false><<<gQKV, 256, 0, stream>>>(Xb, WqkvT, bqkv, QKVf, nullptr,
                                                   NTOK, QKVN, Hc);
        attn_kernel<<<gA, 256, 0, stream>>>(QKVf, attention_mask, Cb);

        // attention-out dense -> Tf (fp32)
        gemm_mfma<false><<<gH, 256, 0, stream>>>(Cb, WaoT, bao + (size_t)l * Hc, Tf, nullptr,
                                                 NTOK, Hc, Hc);
        add_ln_kernel<<<NTOK, 256, 0, stream>>>(Tf, Xf, ln1_g + (size_t)l * Hc,
                                                ln1_b + (size_t)l * Hc, XAf, XAb);

        // FFN1 + gelu -> Hb (bf16)
        gemm_mfma<true><<<gF, 256, 0, stream>>>(XAb, WiT, bi + (size_t)l * Fc, nullptr, Hb,
                                                NTOK, Fc, Hc);
        // FFN2 -> Tf (fp32)
        gemm_mfma<false><<<gH, 256, 0, stream>>>(Hb, WioT, bio + (size_t)l * Hc, Tf, nullptr,
                                                 NTOK, Hc, Fc);
        float* xout = (l == Lc - 1) ? out : Xf;
        add_ln_kernel<<<NTOK, 256, 0, stream>>>(Tf, XAf, ln2_g + (size_t)l * Hc,
                                                ln2_b + (size_t)l * Hc, xout, Xb);
    }
}

// Round 5
// 2358.955 us; speedup vs baseline: 6.5121x; 2.0514x over previous
//
#include <hip/hip_runtime.h>
#include <math.h>

// Problem constants
static constexpr int Bc = 8;
static constexpr int Sc = 512;
static constexpr int Hc = 768;
static constexpr int NHc = 12;
static constexpr int Lc = 12;
static constexpr int Fc = 3072;
static constexpr int DHc = 64;
static constexpr int NTOK = Bc * Sc;      // 4096
static constexpr int QKVN = 3 * Hc;       // 2304

typedef _Float16 h16x8 __attribute__((ext_vector_type(8)));
typedef float f32x4 __attribute__((ext_vector_type(4)));
typedef unsigned short us4 __attribute__((ext_vector_type(4)));
typedef unsigned int u32x4 __attribute__((ext_vector_type(4)));

__device__ __forceinline__ unsigned short f2h(float f) {
    _Float16 h = (_Float16)f;                    // v_cvt_f16_f32, RTE
    return __builtin_bit_cast(unsigned short, h);
}

#define AS1 __attribute__((address_space(1)))
#define AS3 __attribute__((address_space(3)))
__device__ __forceinline__ void gld_lds16(const void* g, void* l) {
    __builtin_amdgcn_global_load_lds((const AS1 void*)g, (AS3 void*)l, 16, 0, 0);
}

// ---------------------------------------------------------------------------
// Embedding + LayerNorm -> fp32 X and fp16 X
// ---------------------------------------------------------------------------
__global__ __launch_bounds__(256) void embed_ln_kernel(
    const int* __restrict__ ids, const int* __restrict__ seg,
    const float* __restrict__ tok, const float* __restrict__ typ,
    const float* __restrict__ pos, const float* __restrict__ g,
    const float* __restrict__ b, float* __restrict__ outf,
    unsigned short* __restrict__ outb)
{
    int t = blockIdx.x;
    int si = t % Sc;
    int id = ids[t], sg = seg[t];
    const float* tp = tok + (size_t)id * Hc;
    const float* yp = typ + (size_t)sg * Hc;
    const float* pp = pos + (size_t)si * Hc;

    float e[3];
    float s = 0.f, s2 = 0.f;
#pragma unroll
    for (int j = 0; j < 3; j++) {
        int h = threadIdx.x + j * 256;
        float v = tp[h] + yp[h] + pp[h];
        e[j] = v; s += v; s2 += v * v;
    }
    __shared__ float red[8];
#pragma unroll
    for (int o = 32; o > 0; o >>= 1) { s += __shfl_xor(s, o); s2 += __shfl_xor(s2, o); }
    int lane = threadIdx.x & 63, wid = threadIdx.x >> 6;
    if (lane == 0) { red[wid] = s; red[4 + wid] = s2; }
    __syncthreads();
    if (threadIdx.x == 0) {
        red[0] = red[0] + red[1] + red[2] + red[3];
        red[4] = red[4] + red[5] + red[6] + red[7];
    }
    __syncthreads();
    float mean = red[0] * (1.0f / Hc);
    float var  = red[4] * (1.0f / Hc) - mean * mean;
    float rstd = rsqrtf(var + 1e-12f);
    float* op = outf + (size_t)t * Hc;
    unsigned short* ob = outb + (size_t)t * Hc;
#pragma unroll
    for (int j = 0; j < 3; j++) {
        int h = threadIdx.x + j * 256;
        float v = g[h] * (e[j] - mean) * rstd + b[h];
        op[h] = v;
        ob[h] = f2h(v);
    }
}

// ---------------------------------------------------------------------------
// (t + residual) -> LayerNorm -> fp32 + fp16
// ---------------------------------------------------------------------------
__global__ __launch_bounds__(256) void add_ln_kernel(
    const float* __restrict__ tin, const float* __restrict__ res,
    const float* __restrict__ g, const float* __restrict__ b,
    float* __restrict__ outf, unsigned short* __restrict__ outb)
{
    int t = blockIdx.x;
    const float* ip = tin + (size_t)t * Hc;
    const float* rp = res + (size_t)t * Hc;

    float e[3];
    float s = 0.f, s2 = 0.f;
#pragma unroll
    for (int j = 0; j < 3; j++) {
        int h = threadIdx.x + j * 256;
        float v = ip[h] + rp[h];
        e[j] = v; s += v; s2 += v * v;
    }
    __shared__ float red[8];
#pragma unroll
    for (int o = 32; o > 0; o >>= 1) { s += __shfl_xor(s, o); s2 += __shfl_xor(s2, o); }
    int lane = threadIdx.x & 63, wid = threadIdx.x >> 6;
    if (lane == 0) { red[wid] = s; red[4 + wid] = s2; }
    __syncthreads();
    if (threadIdx.x == 0) {
        red[0] = red[0] + red[1] + red[2] + red[3];
        red[4] = red[4] + red[5] + red[6] + red[7];
    }
    __syncthreads();
    float mean = red[0] * (1.0f / Hc);
    float var  = red[4] * (1.0f / Hc) - mean * mean;
    float rstd = rsqrtf(var + 1e-12f);
    float* op = outf + (size_t)t * Hc;
    unsigned short* ob = outb + (size_t)t * Hc;
#pragma unroll
    for (int j = 0; j < 3; j++) {
        int h = threadIdx.x + j * 256;
        float v = g[h] * (e[j] - mean) * rstd + b[h];
        op[h] = v;
        ob[h] = f2h(v);
    }
}

// ---------------------------------------------------------------------------
// Weight transpose+convert: src fp32 [K][N] (ld=N) -> dst fp16 [N][K] (ld=K)
// ---------------------------------------------------------------------------
__global__ __launch_bounds__(256) void transpose_conv(
    const float* __restrict__ src, unsigned short* __restrict__ dst,
    int K, int N)
{
    __shared__ float t[32][33];
    int n0 = blockIdx.x * 32, k0 = blockIdx.y * 32;
    int tx = threadIdx.x, ty = threadIdx.y;
#pragma unroll
    for (int j = 0; j < 4; j++)
        t[ty + j * 8][tx] = src[(size_t)(k0 + ty + j * 8) * N + n0 + tx];
    __syncthreads();
#pragma unroll
    for (int j = 0; j < 4; j++)
        dst[(size_t)(n0 + ty + j * 8) * K + k0 + tx] = f2h(t[tx][ty + j * 8]);
}

__global__ void concat3_kernel(const float* __restrict__ a, const float* __restrict__ b,
                               const float* __restrict__ c, float* __restrict__ o)
{
    int i = blockIdx.x * 256 + threadIdx.x;   // < 2304
    float v = (i < 768) ? a[i] : (i < 1536 ? b[i - 768] : c[i - 1536]);
    o[i] = v;
}

// ---------------------------------------------------------------------------
// FP16 MFMA GEMM: C[M,N] = A[M,K] @ Bt[N,K]^T + bias
// OUT: 0 = fp32 to Cf, 1 = gelu+fp16 to Cb, 2 = fp16 to Cb
// ---------------------------------------------------------------------------
template <int OUT>
__global__ __launch_bounds__(256) void gemm_mfma(
    const unsigned short* __restrict__ A,   // [M][K] fp16
    const unsigned short* __restrict__ Bt,  // [N][K] fp16
    const float* __restrict__ bias,         // [N]
    float* __restrict__ Cf,
    unsigned short* __restrict__ Cb,
    int M, int N, int K)
{
    __shared__ __align__(16) unsigned short As[128 * 64];
    __shared__ __align__(16) unsigned short Bs[128 * 64];

    int tid = threadIdx.x;
    int l = tid & 63, w = tid >> 6;
    int m0 = blockIdx.x * 128, n0 = blockIdx.y * 128;
    int lr = l & 15;
    int kg = l >> 4;
    int wr = (w >> 1) * 64, wc = (w & 1) * 64;
    int lx = lr & 7;

    f32x4 acc[4][4] = {};

    for (int k0 = 0; k0 < K; k0 += 64) {
#pragma unroll
        for (int p = 0; p < 4; p++) {
            int i = p * 256 + w * 64 + l;
            int row = i >> 3;
            int slot = (i & 7) ^ (row & 7);
            const unsigned short* ga = A + (size_t)(m0 + row) * K + k0 + slot * 8;
            const unsigned short* gb = Bt + (size_t)(n0 + row) * K + k0 + slot * 8;
            unsigned short* la = As + (size_t)(p * 256 + w * 64) * 8;
            unsigned short* lb = Bs + (size_t)(p * 256 + w * 64) * 8;
            gld_lds16(ga, la);
            gld_lds16(gb, lb);
        }
        asm volatile("s_waitcnt vmcnt(0)" ::: "memory");
        __syncthreads();

#pragma unroll
        for (int kh = 0; kh < 2; kh++) {
            h16x8 av[4], bv[4];
#pragma unroll
            for (int f = 0; f < 4; f++) {
                int sl = (kh * 4 + kg) ^ lx;
                av[f] = *(const h16x8*)(As + (wr + f * 16 + lr) * 64 + sl * 8);
                bv[f] = *(const h16x8*)(Bs + (wc + f * 16 + lr) * 64 + sl * 8);
            }
#pragma unroll
            for (int i = 0; i < 4; i++)
#pragma unroll
                for (int j = 0; j < 4; j++)
                    acc[i][j] = __builtin_amdgcn_mfma_f32_16x16x32_f16(
                        av[i], bv[j], acc[i][j], 0, 0, 0);
        }
        __syncthreads();
    }

#pragma unroll
    for (int i = 0; i < 4; i++) {
        int rbase = m0 + wr + i * 16 + kg * 4;
#pragma unroll
        for (int j = 0; j < 4; j++) {
            int col = n0 + wc + j * 16 + lr;
            float bcol = bias[col];
#pragma unroll
            for (int r = 0; r < 4; r++) {
                float v = acc[i][j][r] + bcol;
                if (OUT == 1) {
                    v = 0.5f * v * (1.0f + erff(v * 0.70710678118654752f));
                    Cb[(size_t)(rbase + r) * N + col] = f2h(v);
                } else if (OUT == 2) {
                    Cb[(size_t)(rbase + r) * N + col] = f2h(v);
                } else {
                    Cf[(size_t)(rbase + r) * N + col] = v;
                }
            }
        }
    }
}

// ---------------------------------------------------------------------------
// MFMA flash attention (fp16 fragments, fp32 softmax/accum).
// QKV fp16 [NTOK][2304]; out ctx fp16 [NTOK][768].
// Block: 256 thr (4 waves), one (b,h), 64 q-rows (16 per wave).
// S^T = mfma(K, Q)  -> lane owns q-col c = l&15, kv rows 16f+4g+r.
// O^T = mfma(Vt, P^T) -> lane owns O[q=c][d=16fm+4g+r].
// ---------------------------------------------------------------------------
__global__ __launch_bounds__(256) void attn_mfma(
    const unsigned short* __restrict__ QKV, const float* __restrict__ mask,
    unsigned short* __restrict__ O)
{
    __shared__ __align__(16) unsigned short Ks[64 * 64];
    __shared__ __align__(16) unsigned short Vt[64 * 64];   // [d][kv], swizzled
    __shared__ float Ml[64];

    int tid = threadIdx.x;
    int l = tid & 63, w = tid >> 6;
    int g = l >> 4, c = l & 15;
    int q0 = blockIdx.x * 64;
    int h = blockIdx.y, bb = blockIdx.z;

    // Q fragment (B-operand of S^T mfma): Q[q=c][d = 32*kh + 8g + j]
    const size_t rowQ = (size_t)(bb * Sc + q0 + w * 16 + c) * QKVN + h * DHc;
    h16x8 qv[2];
    qv[0] = *(const h16x8*)(QKV + rowQ + 8 * g);
    qv[1] = *(const h16x8*)(QKV + rowQ + 32 + 8 * g);

    float m_run = -1e30f, l_run = 0.f;
    f32x4 acc_o[4] = {};
    const float scale = 0.125f;

    for (int kt = 0; kt < Sc; kt += 64) {
        // ---- stage K tile (swizzled source -> linear LDS) ----
        const unsigned short* Kgb = QKV + (size_t)(bb * Sc + kt) * QKVN + Hc + h * DHc;
#pragma unroll
        for (int p = 0; p < 2; p++) {
            int i = p * 256 + tid;
            int row = i >> 3;
            int slot = (i & 7) ^ (row & 7);
            gld_lds16(Kgb + (size_t)row * QKVN + slot * 8, Ks + (size_t)(p * 256 + w * 64) * 8);
        }
        // ---- stage Vt (transposed), coalesced 2B column loads ----
        const unsigned short* Vgb = QKV + (size_t)(bb * Sc + kt) * QKVN + 2 * Hc + h * DHc;
        us4 vv[4];
#pragma unroll
        for (int it = 0; it < 4; it++) {
            int kv0 = (w + it * 4) * 4;
#pragma unroll
            for (int j = 0; j < 4; j++)
                vv[it][j] = Vgb[(size_t)(kv0 + j) * QKVN + l];
        }
#pragma unroll
        for (int it = 0; it < 4; it++) {
            int kv0 = (w + it * 4) * 4;
            *(us4*)(Vt + l * 64 + (((kv0 >> 3) ^ (l & 7)) * 8) + (kv0 & 7)) = vv[it];
        }
        if (tid < 64) Ml[tid] = (1.0f - mask[bb * Sc + kt + tid]) * -10000.0f;
        asm volatile("s_waitcnt vmcnt(0)" ::: "memory");
        __syncthreads();

        // ---- S^T = K @ Q^T : rows kv (4 frags), cols q ----
        f32x4 s[4] = {};
#pragma unroll
        for (int kh = 0; kh < 2; kh++) {
#pragma unroll
            for (int f = 0; f < 4; f++) {
                int row = f * 16 + c;
                h16x8 av = *(const h16x8*)(Ks + row * 64 + (((kh * 4 + g) ^ (row & 7)) * 8));
                s[f] = __builtin_amdgcn_mfma_f32_16x16x32_f16(av, qv[kh], s[f], 0, 0, 0);
            }
        }

        // ---- softmax (per q = c, values spread over g-groups) ----
        f32x4 mv[4];
#pragma unroll
        for (int f = 0; f < 4; f++) mv[f] = *(const f32x4*)&Ml[f * 16 + 4 * g];
        float mx = -1e30f;
#pragma unroll
        for (int f = 0; f < 4; f++)
#pragma unroll
            for (int r = 0; r < 4; r++) {
                float sv = s[f][r] * scale + mv[f][r];
                s[f][r] = sv;
                mx = fmaxf(mx, sv);
            }
        mx = fmaxf(mx, __shfl_xor(mx, 16));
        mx = fmaxf(mx, __shfl_xor(mx, 32));
        float mn = fmaxf(m_run, mx);
        float fs = __expf(m_run - mn);
        m_run = mn;
        float ps = 0.f;
        f32x4 p[4];
#pragma unroll
        for (int f = 0; f < 4; f++)
#pragma unroll
            for (int r = 0; r < 4; r++) {
                float pv = __expf(s[f][r] - mn);
                p[f][r] = pv;
                ps += pv;
            }
        ps += __shfl_xor(ps, 16);
        ps += __shfl_xor(ps, 32);
        l_run = l_run * fs + ps;
#pragma unroll
        for (int fm = 0; fm < 4; fm++)
#pragma unroll
            for (int r = 0; r < 4; r++) acc_o[fm][r] *= fs;

        // ---- pack P to fp16 pairs: pk[f][rp] = (p[f][2rp+1]<<16)|p[f][2rp] ----
        unsigned pk[4][2];
#pragma unroll
        for (int f = 0; f < 4; f++)
#pragma unroll
            for (int rp = 0; rp < 2; rp++)
                pk[f][rp] = ((unsigned)f2h(p[f][2 * rp + 1]) << 16) | f2h(p[f][2 * rp]);

        // ---- PV: O^T += Vt @ P^T ----
        // b_frag for lane (g,c), word t: P[q=c][kv = 32kh + 8g + 2t + {0,1}]
        //   source lane: g_src = 2(g&1) + (t>>1), srcl = g_src*16 + c
        //   f needed   : 2kh + (g>>1)  -- depends on DEST g, so the f-select
        //   must happen AFTER the shuffle (round-3/4 bug: pre-shuffle select
        //   used the source lane's g -> P blocks [8..15]/[16..23] swapped).
#pragma unroll
        for (int kh = 0; kh < 2; kh++) {
            u32x4 bw;
#pragma unroll
            for (int t = 0; t < 4; t++) {
                int srcl = (2 * ((l >> 4) & 1) + (t >> 1)) * 16 + c;
                unsigned lo = __shfl(pk[2 * kh][t & 1], srcl);
                unsigned hi = __shfl(pk[2 * kh + 1][t & 1], srcl);
                bw[t] = (g & 2) ? hi : lo;
            }
            h16x8 bfrag = __builtin_bit_cast(h16x8, bw);
#pragma unroll
            for (int fm = 0; fm < 4; fm++) {
                int row = fm * 16 + c;
                h16x8 av = *(const h16x8*)(Vt + row * 64 + (((kh * 4 + g) ^ (row & 7)) * 8));
                acc_o[fm] = __builtin_amdgcn_mfma_f32_16x16x32_f16(av, bfrag, acc_o[fm], 0, 0, 0);
            }
        }
        __syncthreads();
    }

    // ---- epilogue: O[q=c][d = 16fm + 4g + r] / l ----
    float rl = 1.0f / l_run;
    size_t tokrow = (size_t)(bb * Sc + q0 + w * 16 + c) * Hc + h * DHc;
#pragma unroll
    for (int fm = 0; fm < 4; fm++) {
        us4 ob;
#pragma unroll
        for (int r = 0; r < 4; r++) ob[r] = f2h(acc_o[fm][r] * rl);
        *(us4*)(O + tokrow + fm * 16 + 4 * g) = ob;
    }
}

// ---------------------------------------------------------------------------
extern "C" void kernel_launch(void* const* d_in, const int* in_sizes, int n_in,
                              void* d_out, int out_size, void* d_ws, size_t ws_size,
                              hipStream_t stream)
{
    const int*   input_ids      = (const int*)  d_in[0];
    const int*   segment_ids    = (const int*)  d_in[1];
    const float* attention_mask = (const float*)d_in[2];
    const float* tok_emb = (const float*)d_in[3];
    const float* pos_emb = (const float*)d_in[4];
    const float* type_emb= (const float*)d_in[5];
    const float* emb_g   = (const float*)d_in[6];
    const float* emb_b   = (const float*)d_in[7];
    const float* Wq  = (const float*)d_in[8];  const float* bq  = (const float*)d_in[9];
    const float* Wk  = (const float*)d_in[10]; const float* bk  = (const float*)d_in[11];
    const float* Wv  = (const float*)d_in[12]; const float* bv  = (const float*)d_in[13];
    const float* Wao = (const float*)d_in[14]; const float* bao = (const float*)d_in[15];
    const float* ln1_g = (const float*)d_in[16]; const float* ln1_b = (const float*)d_in[17];
    const float* Wi  = (const float*)d_in[18]; const float* bi  = (const float*)d_in[19];
    const float* Wio = (const float*)d_in[20]; const float* bio = (const float*)d_in[21];
    const float* ln2_g = (const float*)d_in[22]; const float* ln2_b = (const float*)d_in[23];

    float* out = (float*)d_out;

    const size_t NT = (size_t)NTOK * Hc;
    float* Xf  = (float*)d_ws;
    float* XAf = Xf + NT;
    float* Tf  = XAf + NT;
    unsigned short* QKVb = (unsigned short*)(Tf + NT);      // [NTOK][2304]
    unsigned short* Xb  = QKVb + (size_t)NTOK * QKVN;
    unsigned short* XAb = Xb + NT;
    unsigned short* Cb  = XAb + NT;
    unsigned short* Hb  = Cb + NT;                           // [NTOK][3072]
    unsigned short* WqkvT = Hb + (size_t)NTOK * Fc;          // [2304][768]
    unsigned short* WaoT  = WqkvT + (size_t)QKVN * Hc;
    unsigned short* WiT   = WaoT + (size_t)Hc * Hc;          // [3072][768]
    unsigned short* WioT  = WiT + (size_t)Fc * Hc;           // [768][3072]
    float* bqkv = (float*)(WioT + (size_t)Hc * Fc);          // [2304]

    embed_ln_kernel<<<NTOK, 256, 0, stream>>>(input_ids, segment_ids, tok_emb,
                                              type_emb, pos_emb, emb_g, emb_b, Xf, Xb);

    dim3 tb(32, 8);
    dim3 gQKV(NTOK / 128, QKVN / 128);
    dim3 gH(NTOK / 128, Hc / 128);
    dim3 gF(NTOK / 128, Fc / 128);
    dim3 gA(Sc / 64, NHc, Bc);           // 8 x 12 x 8

    for (int l = 0; l < Lc; l++) {
        const float* wq  = Wq  + (size_t)l * Hc * Hc;
        const float* wk  = Wk  + (size_t)l * Hc * Hc;
        const float* wv  = Wv  + (size_t)l * Hc * Hc;
        const float* wao = Wao + (size_t)l * Hc * Hc;
        const float* wi  = Wi  + (size_t)l * Hc * Fc;
        const float* wio = Wio + (size_t)l * Fc * Hc;

        transpose_conv<<<dim3(Hc / 32, Hc / 32), tb, 0, stream>>>(wq, WqkvT, Hc, Hc);
        transpose_conv<<<dim3(Hc / 32, Hc / 32), tb, 0, stream>>>(wk, WqkvT + (size_t)Hc * Hc, Hc, Hc);
        transpose_conv<<<dim3(Hc / 32, Hc / 32), tb, 0, stream>>>(wv, WqkvT + (size_t)2 * Hc * Hc, Hc, Hc);
        transpose_conv<<<dim3(Hc / 32, Hc / 32), tb, 0, stream>>>(wao, WaoT, Hc, Hc);
        transpose_conv<<<dim3(Fc / 32, Hc / 32), tb, 0, stream>>>(wi, WiT, Hc, Fc);
        transpose_conv<<<dim3(Hc / 32, Fc / 32), tb, 0, stream>>>(wio, WioT, Fc, Hc);
        concat3_kernel<<<QKVN / 256, 256, 0, stream>>>(bq + (size_t)l * Hc, bk + (size_t)l * Hc,
                                                       bv + (size_t)l * Hc, bqkv);

        // fused QKV GEMM -> fp16
        gemm_mfma<2><<<gQKV, 256, 0, stream>>>(Xb, WqkvT, bqkv, nullptr, QKVb,
                                               NTOK, QKVN, Hc);
        attn_mfma<<<gA, 256, 0, stream>>>(QKVb, attention_mask, Cb);

        // attention-out dense -> Tf (fp32)
        gemm_mfma<0><<<gH, 256, 0, stream>>>(Cb, WaoT, bao + (size_t)l * Hc, Tf, nullptr,
                                             NTOK, Hc, Hc);
        add_ln_kernel<<<NTOK, 256, 0, stream>>>(Tf, Xf, ln1_g + (size_t)l * Hc,
                                                ln1_b + (size_t)l * Hc, XAf, XAb);

        // FFN1 + gelu -> Hb (fp16)
        gemm_mfma<1><<<gF, 256, 0, stream>>>(XAb, WiT, bi + (size_t)l * Fc, nullptr, Hb,
                                             NTOK, Fc, Hc);
        // FFN2 -> Tf (fp32)
        gemm_mfma<0><<<gH, 256, 0, stream>>>(Hb, WioT, bio + (size_t)l * Hc, Tf, nullptr,
                                             NTOK, Hc, Fc);
        float* xout = (l == Lc - 1) ? out : Xf;
        add_ln_kernel<<<NTOK, 256, 0, stream>>>(Tf, XAf, ln2_g + (size_t)l * Hc,
                                                ln2_b + (size_t)l * Hc, xout, Xb);
    }
}